// Round 10
// baseline (369.283 us; speedup 1.0000x reference)
//
#include <hip/hip_runtime.h>
#include <stdint.h>
#include <math.h>

typedef __attribute__((ext_vector_type(8))) short bf16x8;   // MFMA A/B frag (8 bf16)
typedef __attribute__((ext_vector_type(4))) float f32x4;    // MFMA C/D frag
typedef __attribute__((ext_vector_type(4))) unsigned short us4;
typedef __attribute__((ext_vector_type(8))) unsigned short us8;

#define BB   8
#define SS   512
#define HH   1024
#define NHH  16
#define DHH  64
#define FFF  4096
#define MTOK 4096  // B*S
#define QKVN 3072  // fused QKV output width

__device__ __forceinline__ unsigned short f2bf(float f) {
  union { float f; uint32_t u; } c; c.f = f;
  uint32_t u = c.u;
  return (unsigned short)((u + 0x7fffu + ((u >> 16) & 1u)) >> 16);  // RNE
}
__device__ __forceinline__ float bf2f(unsigned short u) {
  union { uint32_t u; float f; } c; c.u = ((uint32_t)u) << 16; return c.f;
}

// tanh-GELU via sigmoid: 0.5x(1+tanh(u)) = x / (1 + e^{-2u}); __expf -> v_exp_f32
__device__ __forceinline__ float gelu_tanh(float x) {
  float u = 0.7978845608028654f * (x + 0.044715f * x * x * x);
  return x / (1.0f + __expf(-2.0f * u));
}

// async global->LDS, 16B per lane; LDS dest = wave-uniform base + lane*16 (m104)
__device__ __forceinline__ void gload16(const unsigned short* g, unsigned short* l) {
  __builtin_amdgcn_global_load_lds(
      (const __attribute__((address_space(1))) unsigned short*)g,
      (__attribute__((address_space(3))) unsigned short*)l, 16, 0, 0);
}

// ---------------- cast f32 -> bf16 (vectorized) ----------------
__global__ void cast_f32_to_bf16(const float* __restrict__ in,
                                 unsigned short* __restrict__ out, int n4) {
  int i = blockIdx.x * blockDim.x + threadIdx.x;
  if (i >= n4) return;
  f32x4 v = *(const f32x4*)(in + (size_t)i * 4);
  us4 o;
  #pragma unroll
  for (int j = 0; j < 4; ++j) o[j] = f2bf(v[j]);
  *(us4*)(out + (size_t)i * 4) = o;
}

// ---------------- mask -> bf16 additive term: (1-mask)*-10000 - 8 ----------------
__global__ void mask_to_adder(const int* __restrict__ mask,
                              unsigned short* __restrict__ out, int n8) {
  int i = blockIdx.x * 256 + threadIdx.x;
  if (i >= n8) return;
  us8 o;
  #pragma unroll
  for (int j = 0; j < 8; ++j)
    o[j] = f2bf((float)(1 - mask[(size_t)i * 8 + j]) * -10000.0f - 8.0f);
  *(us8*)(out + (size_t)i * 8) = o;
}

// ---------------- fused weight prep: 6 transposes + bias concat ----------------
__global__ void prep_weights(
    const float* __restrict__ Wq, const float* __restrict__ Wk,
    const float* __restrict__ Wv, const float* __restrict__ Wao,
    const float* __restrict__ Wi, const float* __restrict__ Wo,
    const float* __restrict__ bq, const float* __restrict__ bk,
    const float* __restrict__ bv,
    unsigned short* __restrict__ WqkvT, unsigned short* __restrict__ WaoT,
    unsigned short* __restrict__ WiT, unsigned short* __restrict__ WoT,
    float* __restrict__ bqkv) {
  __shared__ float tile[32][33];
  const int bid = blockIdx.x;
  const int tx = threadIdx.x, ty = threadIdx.y;
  if (bid >= 12288) {
    int i = (bid - 12288) * 256 + ty * 32 + tx;
    bqkv[i] = i < HH ? bq[i] : (i < 2 * HH ? bk[i - HH] : bv[i - 2 * HH]);
    return;
  }
  const float* src; unsigned short* dst; int R, C, bx, by;
  if (bid < 4096) {
    int w6 = bid >> 10, i = bid & 1023;
    src = w6 == 0 ? Wq : w6 == 1 ? Wk : w6 == 2 ? Wv : Wao;
    dst = w6 == 3 ? WaoT : WqkvT + (size_t)w6 * HH * HH;
    R = HH; C = HH; bx = i & 31; by = i >> 5;
  } else if (bid < 8192) {
    int i = bid - 4096; src = Wi; dst = WiT; R = HH; C = FFF; bx = i & 127; by = i >> 7;
  } else {
    int i = bid - 8192; src = Wo; dst = WoT; R = FFF; C = HH; bx = i & 31; by = i >> 5;
  }
  const int bc = bx * 32, br = by * 32;
  #pragma unroll
  for (int i = 0; i < 32; i += 8)
    tile[ty + i][tx] = src[(size_t)(br + ty + i) * C + bc + tx];
  __syncthreads();
  #pragma unroll
  for (int i = 0; i < 32; i += 8)
    dst[(size_t)(bc + ty + i) * R + br + tx] = f2bf(tile[tx][ty + i]);
}

// ---------------- 128x256 8-wave GEMM, triple-buffered depth-2 prefetch ---------
// C[M,N] = A[M,K](bf16) * BT[N,K](bf16)^T. 512 thr = 8 waves (2M x 4N), wave out
// 64x64 (4x4 frags). BK=64, LDS 3 x (A 16KB + B 32KB) = 144KB, 1 block/CU.
// Depth-2 counted vmcnt: tile kt+2 issued at kt's top; vmcnt(12) (= 6 loads/tile
// x 2 tiles in flight) waits only for tile kt -> load age ~2 tile-periods > HBM
// latency. XOR-swizzled LDS (0 conflicts, r7-verified) + setprio.
// EPI: 0 = bias->bf16; 2 = bias+gelu->bf16; 3 = f32 split-K partial (no bias).
template <int EPI>
__global__ __launch_bounds__(512, 2) void gemm3(
    const unsigned short* __restrict__ A, const unsigned short* __restrict__ BT,
    const float* __restrict__ bias, unsigned short* __restrict__ Cb,
    float* __restrict__ Cf, int M, int N, int K, int KSL) {
  __shared__ unsigned short Asl[3][128 * 64];
  __shared__ unsigned short Bsl[3][256 * 64];
  const int t = threadIdx.x;
  const int w = t >> 6, lane = t & 63;
  const int g = lane >> 4, fr = lane & 15;
  const int wr = w >> 2, wc = w & 3;  // 2 x 4 wave grid
  const int m0 = blockIdx.x * 128, n0 = blockIdx.y * 256;
  const int k0 = blockIdx.z * KSL;
  const int nk = KSL >> 6;

  // staging: linear LDS [row][chunk]; source chunk pre-swizzled (t&7)^(row&7)
  const int srow = t >> 3;                  // 0..63
  const int schunk = (t & 7) ^ (srow & 7);
  const unsigned short* gA = A + (size_t)(m0 + srow) * K + k0 + schunk * 8;
  const unsigned short* gB = BT + (size_t)(n0 + srow) * K + k0 + schunk * 8;

  f32x4 acc[4][4] = {};

  // per thread per tile: A 2 loads (rows j*64+srow, j=0..1), B 4 loads (j=0..3)
  #define STAGE(buf, kt)                                                  \
    do {                                                                  \
      _Pragma("unroll")                                                   \
      for (int j = 0; j < 2; ++j)                                         \
        gload16(gA + (size_t)(kt) * 64 + (size_t)j * 64 * K,              \
                &Asl[buf][j * 4096 + w * 512]);                           \
      _Pragma("unroll")                                                   \
      for (int j = 0; j < 4; ++j)                                         \
        gload16(gB + (size_t)(kt) * 64 + (size_t)j * 64 * K,              \
                &Bsl[buf][j * 4096 + w * 512]);                           \
    } while (0)

  STAGE(0, 0);
  STAGE(1, 1);  // all call sites have nk >= 8
  int cb_ = 0, sb_ = 2;
  for (int kt = 0; kt < nk; ++kt) {
    if (kt + 2 < nk) {
      STAGE(sb_, kt + 2);
      asm volatile("s_waitcnt vmcnt(12)" ::: "memory");  // tile kt landed; 2 ahead
    } else if (kt + 1 < nk) {
      asm volatile("s_waitcnt vmcnt(6)" ::: "memory");   // tile kt landed; 1 ahead
    } else {
      asm volatile("s_waitcnt vmcnt(0)" ::: "memory");
    }
    __builtin_amdgcn_s_barrier();
    bf16x8 af[4][2], bfr[4][2];
    #pragma unroll
    for (int m = 0; m < 4; ++m)
      #pragma unroll
      for (int kk = 0; kk < 2; ++kk)
        af[m][kk] = *(const bf16x8*)(
            &Asl[cb_][(wr * 64 + m * 16 + fr) * 64 + (((kk * 4 + g) ^ (fr & 7)) * 8)]);
    #pragma unroll
    for (int n = 0; n < 4; ++n)
      #pragma unroll
      for (int kk = 0; kk < 2; ++kk)
        bfr[n][kk] = *(const bf16x8*)(
            &Bsl[cb_][(wc * 64 + n * 16 + fr) * 64 + (((kk * 4 + g) ^ (fr & 7)) * 8)]);
    __builtin_amdgcn_s_setprio(1);
    #pragma unroll
    for (int kk = 0; kk < 2; ++kk)
      #pragma unroll
      for (int m = 0; m < 4; ++m)
        #pragma unroll
        for (int n = 0; n < 4; ++n)
          acc[m][n] = __builtin_amdgcn_mfma_f32_16x16x32_bf16(
              af[m][kk], bfr[n][kk], acc[m][n], 0, 0, 0);
    __builtin_amdgcn_s_setprio(0);
    __builtin_amdgcn_s_barrier();  // readers of buf[cb_] done before its re-stage
    cb_ = cb_ == 2 ? 0 : cb_ + 1;
    sb_ = sb_ == 2 ? 0 : sb_ + 1;
  }
  #undef STAGE

  // epilogue: D layout col=lane&15, row=(lane>>4)*4+r  [m89-verified]
  #pragma unroll
  for (int mf = 0; mf < 4; ++mf) {
    const int gr0 = m0 + wr * 64 + mf * 16 + g * 4;
    #pragma unroll
    for (int nf = 0; nf < 4; ++nf) {
      const int gc = n0 + wc * 64 + nf * 16 + fr;
      const float bb = (EPI == 3) ? 0.f : bias[gc];
      #pragma unroll
      for (int r = 0; r < 4; ++r) {
        float v = acc[mf][nf][r] + bb;
        if (EPI == 2) v = gelu_tanh(v);
        if (EPI == 3)
          Cf[(size_t)blockIdx.z * M * N + (size_t)(gr0 + r) * N + gc] = v;
        else
          Cb[(size_t)(gr0 + r) * N + gc] = f2bf(v);
      }
    }
  }
}

// ---------------- fused attention (fixed-offset softmax, reg-dbuf, XCD-grouped) --
// r8-verified. 1D grid 1024: b = bid&7 (XCD key), h = (bid>>3)&15, qt = bid>>7.
__global__ __launch_bounds__(256) void attn_fused(
    const unsigned short* __restrict__ QKV, const unsigned short* __restrict__ adder,
    unsigned short* __restrict__ ctx) {
  __shared__ unsigned short Ks[64][72];      // [kv][d] straight (+8 pad)
  __shared__ unsigned short Vt[64][72];      // [d][kv], 16B-chunk XOR swizzled
  __shared__ unsigned short Al[64][72];      // adder tile [qrow][kc]
  __shared__ unsigned short Pl[4][16][72];   // per-wave P round-trip
  const int t = threadIdx.x, w = t >> 6, lane = t & 63;
  const int g = lane >> 4, fr = lane & 15;
  const int bid = blockIdx.x;
  const int b = bid & 7, h = (bid >> 3) & 15, qt = bid >> 7;
  const int colh = h * 64;
  const int qrow0 = b * SS + qt * 64 + w * 16;

  // Q fragment, pre-scaled by 1/sqrt(64)=0.125 (exact in bf16: exponent shift)
  bf16x8 aq[2];
  #pragma unroll
  for (int ks = 0; ks < 2; ++ks) {
    union { us8 u; bf16x8 b; } cv;
    cv.u = *(const us8*)(QKV + (size_t)(qrow0 + fr) * QKVN + colh + ks * 32 + g * 8);
    #pragma unroll
    for (int j = 0; j < 8; ++j) cv.u[j] = f2bf(bf2f(cv.u[j]) * 0.125f);
    aq[ks] = cv.b;
  }

  float lrow[4] = {0.f, 0.f, 0.f, 0.f};
  f32x4 oacc[4] = {};

  us8 kr[2], vr[2], ar[2];
  #define ALOAD(kt)                                                          \
    _Pragma("unroll")                                                        \
    for (int i = 0; i < 2; ++i) {                                            \
      int c = i * 256 + t, row = c >> 3, ko = (c & 7) * 8;                   \
      const size_t gb = (size_t)(b * SS + (kt) * 64 + row) * QKVN + colh + ko; \
      kr[i] = *(const us8*)(QKV + HH + gb);                                  \
      vr[i] = *(const us8*)(QKV + 2 * HH + gb);                              \
      ar[i] = *(const us8*)(adder + (size_t)(b * SS + qt * 64 + row) * SS + (kt) * 64 + ko); \
    }

  ALOAD(0);
  for (int kt = 0; kt < 8; ++kt) {
    __syncthreads();
    #pragma unroll
    for (int i = 0; i < 2; ++i) {
      int c = i * 256 + t, row = c >> 3, ko = (c & 7) * 8;
      *(us8*)(&Ks[row][ko]) = kr[i];
      *(us8*)(&Al[row][ko]) = ar[i];
      const int xo = (row >> 3) ^ (c & 7);
      #pragma unroll
      for (int j = 0; j < 8; ++j) Vt[ko + j][xo * 8 + (row & 7)] = vr[i][j];
    }
    __syncthreads();
    if (kt < 7) ALOAD(kt + 1);

    // S = (Q/8) K^T + (adder-8)
    f32x4 sacc[4];
    #pragma unroll
    for (int cb = 0; cb < 4; ++cb)
      #pragma unroll
      for (int r = 0; r < 4; ++r)
        sacc[cb][r] = bf2f(Al[w * 16 + g * 4 + r][cb * 16 + fr]);
    #pragma unroll
    for (int ks = 0; ks < 2; ++ks)
      #pragma unroll
      for (int cb = 0; cb < 4; ++cb) {
        bf16x8 bk = *(const bf16x8*)(&Ks[cb * 16 + fr][ks * 32 + g * 8]);
        sacc[cb] = __builtin_amdgcn_mfma_f32_16x16x32_bf16(aq[ks], bk, sacc[cb], 0, 0, 0);
      }

    // p = exp(s); row partial; stage P for PV
    #pragma unroll
    for (int cb = 0; cb < 4; ++cb)
      #pragma unroll
      for (int r = 0; r < 4; ++r) {
        float pv = __expf(sacc[cb][r]);
        lrow[r] += pv;
        Pl[w][g * 4 + r][cb * 16 + fr] = f2bf(pv);
      }
    asm volatile("s_waitcnt lgkmcnt(0)" ::: "memory");

    // O += P V
    #pragma unroll
    for (int ks = 0; ks < 2; ++ks) {
      bf16x8 pa = *(const bf16x8*)(&Pl[w][fr][ks * 32 + g * 8]);
      #pragma unroll
      for (int nb = 0; nb < 4; ++nb) {
        const int dd = nb * 16 + fr;
        const int ch = (ks * 4 + g) ^ ((dd >> 3) & 7);
        bf16x8 bv = *(const bf16x8*)(&Vt[dd][ch * 8]);
        oacc[nb] = __builtin_amdgcn_mfma_f32_16x16x32_bf16(pa, bv, oacc[nb], 0, 0, 0);
      }
    }
  }
  #undef ALOAD

  #pragma unroll
  for (int off = 1; off < 16; off <<= 1)
    #pragma unroll
    for (int r = 0; r < 4; ++r)
      lrow[r] += __shfl_xor(lrow[r], off, 64);

  #pragma unroll
  for (int nb = 0; nb < 4; ++nb)
    #pragma unroll
    for (int r = 0; r < 4; ++r) {
      float v = oacc[nb][r] / lrow[r];
      ctx[(size_t)(qrow0 + g * 4 + r) * HH + colh + nb * 16 + fr] = f2bf(v);
    }
}

// ---------------- split-K reduce + bias + residual + LayerNorm (row=1024) --------
__global__ __launch_bounds__(256) void residual_ln_red(
    const float* __restrict__ part, int MN, int S,
    const float* __restrict__ bias, const float* __restrict__ res,
    const float* __restrict__ gamma, const float* __restrict__ beta,
    float* __restrict__ outf, unsigned short* __restrict__ outb) {
  __shared__ float red[8];
  const int row = blockIdx.x, t = threadIdx.x, w = t >> 6, lane = t & 63;
  const size_t base = (size_t)row * HH + t * 4;
  f32x4 v = *(const f32x4*)(res + base);
  v += *(const f32x4*)(bias + t * 4);
  for (int s = 0; s < S; ++s) v += *(const f32x4*)(part + (size_t)s * MN + base);
  float sm = v[0] + v[1] + v[2] + v[3];
  #pragma unroll
  for (int off = 32; off; off >>= 1) sm += __shfl_xor(sm, off, 64);
  if (lane == 0) red[w] = sm;
  __syncthreads();
  const float mean = (red[0] + red[1] + red[2] + red[3]) * (1.0f / HH);
  f32x4 d;
  #pragma unroll
  for (int j = 0; j < 4; ++j) d[j] = v[j] - mean;
  float q = d[0] * d[0] + d[1] * d[1] + d[2] * d[2] + d[3] * d[3];
  #pragma unroll
  for (int off = 32; off; off >>= 1) q += __shfl_xor(q, off, 64);
  if (lane == 0) red[4 + w] = q;
  __syncthreads();
  const float var = (red[4] + red[5] + red[6] + red[7]) * (1.0f / HH);
  const float rstd = rsqrtf(var + 1e-12f);
  f32x4 gv = *(const f32x4*)(gamma + t * 4);
  f32x4 bv = *(const f32x4*)(beta + t * 4);
  f32x4 o;
  #pragma unroll
  for (int j = 0; j < 4; ++j) o[j] = d[j] * rstd * gv[j] + bv[j];
  *(f32x4*)(outf + base) = o;
  if (outb) {
    us4 ob;
    #pragma unroll
    for (int j = 0; j < 4; ++j) ob[j] = f2bf(o[j]);
    *(us4*)(outb + base) = ob;
  }
}

// ---------------- launch ----------------
extern "C" void kernel_launch(void* const* d_in, const int* in_sizes, int n_in,
                              void* d_out, int out_size, void* d_ws, size_t ws_size,
                              hipStream_t stream) {
  const float* lin  = (const float*)d_in[0];
  const int* amask  = (const int*)d_in[1];
  const float* Wq   = (const float*)d_in[2];  const float* bq  = (const float*)d_in[3];
  const float* Wk   = (const float*)d_in[4];  const float* bk  = (const float*)d_in[5];
  const float* Wv   = (const float*)d_in[6];  const float* bv  = (const float*)d_in[7];
  const float* Wao  = (const float*)d_in[8];  const float* bao = (const float*)d_in[9];
  const float* g1   = (const float*)d_in[10]; const float* be1 = (const float*)d_in[11];
  const float* Wi   = (const float*)d_in[12]; const float* bi  = (const float*)d_in[13];
  const float* Wo   = (const float*)d_in[14]; const float* bo  = (const float*)d_in[15];
  const float* g2   = (const float*)d_in[16]; const float* be2 = (const float*)d_in[17];

  char* p = (char*)d_ws;
  const size_t MB = 1024ull * 1024;
  unsigned short* Xb    = (unsigned short*)(p + 0);        // 8MB  [4096,1024] bf16
  unsigned short* WqkvT = (unsigned short*)(p + 8 * MB);   // 6MB  [3072,1024] bf16
  unsigned short* WaoT  = (unsigned short*)(p + 14 * MB);  // 2MB
  unsigned short* WiT   = (unsigned short*)(p + 16 * MB);  // 8MB  [4096,1024]
  unsigned short* WoT   = (unsigned short*)(p + 24 * MB);  // 8MB  [1024,4096]
  unsigned short* QKVb  = (unsigned short*)(p + 32 * MB);  // 24MB [4096,3072]
  unsigned short* Ctx   = (unsigned short*)(p + 56 * MB);  // 8MB
  float*          Ao    = (float*)(p + 80 * MB);           // 16MB attn_out f32
  unsigned short* Aob   = (unsigned short*)(p + 96 * MB);  // 8MB  attn_out bf16
  unsigned short* Inter = (unsigned short*)(p + 104 * MB); // 32MB [4096,4096] bf16
  float*          bqkv  = (float*)(p + 64 * MB);           // 12KB (dead after QKV)
  unsigned short* adder = (unsigned short*)(p + 66 * MB);  // 4MB  bf16 [B,S,S]
  const int SPL = 2;
  float* PartAO = (float*)(p + 104 * MB);  // overlaps Inter (written later)
  float* PartF2 = (float*)(p + 32 * MB);   // overlaps dead QKVb+Ctx
  (void)in_sizes; (void)n_in; (void)out_size; (void)ws_size;

  cast_f32_to_bf16<<<(MTOK * HH / 4) / 256, 256, 0, stream>>>(lin, Xb, MTOK * HH / 4);
  mask_to_adder<<<(BB * SS * SS / 8) / 256, 256, 0, stream>>>(amask, adder, BB * SS * SS / 8);
  prep_weights<<<12300, dim3(32, 8), 0, stream>>>(Wq, Wk, Wv, Wao, Wi, Wo, bq, bk, bv,
                                                  WqkvT, WaoT, WiT, WoT, bqkv);

  // fused QKV: [4096,3072], grid 32x12 = 384 blocks
  gemm3<0><<<dim3(MTOK / 128, QKVN / 256), 512, 0, stream>>>(
      Xb, WqkvT, bqkv, QKVb, nullptr, MTOK, QKVN, HH, HH);

  attn_fused<<<SS / 64 * BB * NHH, 256, 0, stream>>>(QKVb, adder, Ctx);

  // attn-out projection, split-K SPL=2: 32x4x2 = 256 blocks
  gemm3<3><<<dim3(MTOK / 128, HH / 256, SPL), 512, 0, stream>>>(
      Ctx, WaoT, nullptr, nullptr, PartAO, MTOK, HH, HH, HH / SPL);
  residual_ln_red<<<MTOK, 256, 0, stream>>>(PartAO, MTOK * HH, SPL, bao, lin, g1, be1, Ao, Aob);

  // FFN1: [4096,4096] + gelu, grid 32x16 = 512 blocks
  gemm3<2><<<dim3(MTOK / 128, FFF / 256), 512, 0, stream>>>(
      Aob, WiT, bi, Inter, nullptr, MTOK, FFF, HH, HH);

  // FFN2: [4096,1024], K=4096, split-K SPL=2: 32x4x2 = 256 blocks
  gemm3<3><<<dim3(MTOK / 128, HH / 256, SPL), 512, 0, stream>>>(
      Inter, WoT, nullptr, nullptr, PartF2, MTOK, HH, FFF, FFF / SPL);
  residual_ln_red<<<MTOK, 256, 0, stream>>>(PartF2, MTOK * HH, SPL, bo, Ao, g2, be2,
                                            (float*)d_out, nullptr);
}